// Round 1
// baseline (846.055 us; speedup 1.0000x reference)
//
#include <hip/hip_runtime.h>
#include <stdint.h>

typedef unsigned short u16;
typedef short short8 __attribute__((ext_vector_type(8)));
typedef float floatx4 __attribute__((ext_vector_type(4)));

#define S_LEN 2048
#define NB 2
#define NH 8
#define R_TOK (NB * S_LEN)  // 4096

// log2(10000)
#define L2_THETA 13.287712379549449f

__device__ inline u16 f2bf(float f) {
  union { float f; uint32_t u; } x; x.f = f;
  uint32_t r = (x.u + 0x7fffu + ((x.u >> 16) & 1u)) >> 16;
  return (u16)r;
}
__device__ inline float bf2f(u16 h) {
  union { uint32_t u; float f; } x; x.u = ((uint32_t)h) << 16;
  return x.f;
}
__device__ inline floatx4 mfma16(short8 a, short8 b, floatx4 c) {
  return __builtin_amdgcn_mfma_f32_16x16x32_bf16(a, b, c, 0, 0, 0);
}

// ---------------- fp32 -> bf16 convert (vectorized) ----------------
__global__ void k_f2bf(const float* __restrict__ in, u16* __restrict__ out, int n4) {
  int i = blockIdx.x * blockDim.x + threadIdx.x;
  if (i < n4) {
    float4 v = ((const float4*)in)[i];
    ushort4 o;
    o.x = f2bf(v.x); o.y = f2bf(v.y); o.z = f2bf(v.z); o.w = f2bf(v.w);
    ((ushort4*)out)[i] = o;
  }
}

// ---------------- concat [w_dq | w_dkv_kr] -> bf16 (1024 x 320), concat bias ----------------
__global__ void k_prep_wa(const float* __restrict__ wdq, const float* __restrict__ wdkv,
                          const float* __restrict__ bdq, const float* __restrict__ bdkv,
                          u16* __restrict__ wa, float* __restrict__ biasA) {
  int i = blockIdx.x * 256 + threadIdx.x;
  if (i < 1024 * 320) {
    int k = i / 320, n = i - k * 320;
    float v = (n < 128) ? wdq[k * 128 + n] : wdkv[k * 192 + (n - 128)];
    wa[i] = f2bf(v);
  }
  if (i < 320) biasA[i] = (i < 128) ? bdq[i] : bdkv[i - 128];
}

// ---------------- generic bf16 MFMA GEMM: C(MxN) = A(MxK) @ B(KxN) + bias ----------------
// 64x64 tile per block (4 waves, each wave: 16 rows x 64 cols). K multiple of 32,
// M,N multiples of 64. OUT_BF: 1 -> bf16 output, 0 -> fp32 output.
template <int OUT_BF>
__global__ __launch_bounds__(256) void k_gemm(const u16* __restrict__ A,
                                              const u16* __restrict__ Bm,
                                              const float* __restrict__ bias,
                                              void* __restrict__ Cout,
                                              int M, int N, int K) {
  __shared__ u16 Alds[64 * 40];  // row-major, stride 40 (pad: 2-way banks, 16B aligned)
  __shared__ u16 Blds[64 * 40];  // transposed: [n][k], stride 40
  const int tid = threadIdx.x;
  const int wave = tid >> 6, lane = tid & 63;
  const int lane15 = lane & 15, quad = lane >> 4;
  const int m0 = blockIdx.y * 64, n0 = blockIdx.x * 64;

  floatx4 acc[4];
#pragma unroll
  for (int i = 0; i < 4; ++i) acc[i] = (floatx4){0.f, 0.f, 0.f, 0.f};

  const int ar = tid >> 2, aseg = (tid & 3) * 8;   // A stage: 64 rows x 4 segs of 8
  const int bk = tid >> 3, bn8 = (tid & 7) * 8;    // B stage: 32 k-rows x 8 segs of 8

  for (int k0 = 0; k0 < K; k0 += 32) {
    __syncthreads();
    {  // stage A tile 64x32
      const u16* src = A + (size_t)(m0 + ar) * K + k0 + aseg;
      *(short8*)&Alds[ar * 40 + aseg] = *(const short8*)src;
    }
    {  // stage B tile 32x64, transposed into LDS
      const u16* src = Bm + (size_t)(k0 + bk) * N + n0 + bn8;
      short8 v = *(const short8*)src;
#pragma unroll
      for (int j = 0; j < 8; ++j) Blds[(bn8 + j) * 40 + bk] = (u16)v[j];
    }
    __syncthreads();
    short8 a = *(const short8*)&Alds[(wave * 16 + lane15) * 40 + quad * 8];
#pragma unroll
    for (int nb = 0; nb < 4; ++nb) {
      short8 b = *(const short8*)&Blds[(nb * 16 + lane15) * 40 + quad * 8];
      acc[nb] = mfma16(a, b, acc[nb]);
    }
  }
#pragma unroll
  for (int nb = 0; nb < 4; ++nb) {
#pragma unroll
    for (int r = 0; r < 4; ++r) {
      int row = m0 + wave * 16 + quad * 4 + r;
      int col = n0 + nb * 16 + lane15;
      float v = acc[nb][r] + bias[col];
      if (OUT_BF)
        ((u16*)Cout)[(size_t)row * N + col] = f2bf(v);
      else
        ((float*)Cout)[(size_t)row * N + col] = v;
    }
  }
}

// ---------------- stage-A epilogue: rmsnorm(cq), rmsnorm(ckv), rope(k_rope) ----------------
// t0: (R, 320) fp32 = [cq_pre(128) | ckv_pre(128) | k_rope_raw(64)]
__global__ void k_stagea(const float* __restrict__ t0, const float* __restrict__ qnw,
                         const float* __restrict__ kvnw, const int* __restrict__ pos_ids,
                         u16* __restrict__ cq, u16* __restrict__ ckv,
                         u16* __restrict__ krope) {
  int r = blockIdx.x, tid = threadIdx.x;  // 128 threads
  const float* row = t0 + (size_t)r * 320;
  float a = row[tid];
  float b = row[128 + tid];
  float sa = a * a, sb = b * b;
#pragma unroll
  for (int d = 1; d < 64; d <<= 1) {
    sa += __shfl_xor(sa, d);
    sb += __shfl_xor(sb, d);
  }
  __shared__ float red[4];
  if ((tid & 63) == 0) { red[(tid >> 6) * 2] = sa; red[(tid >> 6) * 2 + 1] = sb; }
  __syncthreads();
  sa = red[0] + red[2];
  sb = red[1] + red[3];
  float ra = rsqrtf(sa * (1.0f / 128.0f) + 1e-8f);
  float rb = rsqrtf(sb * (1.0f / 128.0f) + 1e-8f);
  cq[(size_t)r * 128 + tid] = f2bf(qnw[tid] * a * ra);
  ckv[(size_t)r * 128 + tid] = f2bf(kvnw[tid] * b * rb);
  if (tid < 32) {
    float xe = row[256 + 2 * tid], xo = row[256 + 2 * tid + 1];
    float p = (float)pos_ids[r];
    float freq = exp2f(-(2.0f * tid / 64.0f) * L2_THETA);
    float ang = p * freq;
    float c = cosf(ang), s = sinf(ang);
    krope[(size_t)r * 64 + 2 * tid] = f2bf(xe * c - xo * s);
    krope[(size_t)r * 64 + 2 * tid + 1] = f2bf(xe * s + xo * c);
  }
}

// ---------------- stage-B epilogue: rope(q_rope) + scatter to (B,H,S,128) ----------------
__global__ void k_stageb(const u16* __restrict__ q, const int* __restrict__ pos_ids,
                         u16* __restrict__ qstates) {
  int r = blockIdx.x, tid = threadIdx.x;  // 256 threads
  int b = r >> 11, s = r & (S_LEN - 1);
  float p = (float)pos_ids[r];
#pragma unroll
  for (int i = 0; i < 4; ++i) {
    int idx = tid + i * 256;  // h*128 + d
    int h = idx >> 7, d = idx & 127;
    float val;
    if (d < 96) {
      val = bf2f(q[(size_t)r * 1024 + h * 96 + d]);
    } else {
      int j = d - 96, pr = j >> 1;
      float xe = bf2f(q[(size_t)r * 1024 + 768 + h * 32 + 2 * pr]);
      float xo = bf2f(q[(size_t)r * 1024 + 768 + h * 32 + 2 * pr + 1]);
      float freq = exp2f(-(2.0f * pr / 32.0f) * L2_THETA);
      float ang = p * freq;
      float c = cosf(ang), sn = sinf(ang);
      val = (j & 1) ? (xe * sn + xo * c) : (xe * c - xo * sn);
    }
    qstates[((size_t)(b * NH + h) * S_LEN + s) * 128 + d] = f2bf(val);
  }
}

// ---------------- flash attention: one block = (b,h) x 64 q-rows; wave = 16 q-rows ----------------
// qstates (B,H,S,128); kv (R,2560): [h*64+d]=k_nope, [512+h*256+n]=v; krope (R,64)
// out attn (R, 2048): [r, h*256+n]
__global__ __launch_bounds__(256) void k_attn(const u16* __restrict__ qstates,
                                              const u16* __restrict__ kv,
                                              const u16* __restrict__ krope,
                                              u16* __restrict__ attn_out) {
  const int qblk = blockIdx.x;  // 0..31
  const int pair = blockIdx.y;  // 0..15
  const int b = pair >> 3, h = pair & 7;
  const int tid = threadIdx.x;
  const int wave = tid >> 6, lane = tid & 63;
  const int lane15 = lane & 15, quad = lane >> 4;

  __shared__ u16 Klds[32 * 136];      // rows: k_nope(64)|k_rope(64), stride 136
  __shared__ u16 Vlds[256 * 40];      // transposed [n][k], stride 40
  __shared__ u16 Plds[4][16 * 40];    // per-wave P 16x32, stride 40

  const int qrow0 = qblk * 64 + wave * 16;
  short8 qfrag[4];
  {
    const u16* qb = qstates + ((size_t)(b * NH + h) * S_LEN + qrow0 + lane15) * 128 + quad * 8;
#pragma unroll
    for (int c = 0; c < 4; ++c) qfrag[c] = *(const short8*)(qb + c * 32);
  }

  floatx4 o_acc[16];
#pragma unroll
  for (int g = 0; g < 16; ++g) o_acc[g] = (floatx4){0.f, 0.f, 0.f, 0.f};
  float m_i[4] = {-1e30f, -1e30f, -1e30f, -1e30f};
  float l_i[4] = {0.f, 0.f, 0.f, 0.f};
  const float scale = 0.08838834764831845f;  // 1/sqrt(128)

  const int kr = tid >> 3, kseg = tid & 7;

  for (int kk0 = 0; kk0 < S_LEN; kk0 += 32) {
    __syncthreads();
    {  // stage K tile: 32 rows x 128 (k_nope | k_rope)
      size_t rowg = (size_t)b * S_LEN + kk0 + kr;
      const u16* src = (kseg < 4) ? (kv + rowg * 2560 + h * 64 + kseg * 16)
                                  : (krope + rowg * 64 + (kseg - 4) * 16);
      short8 v0 = *(const short8*)src;
      short8 v1 = *(const short8*)(src + 8);
      *(short8*)&Klds[kr * 136 + kseg * 16] = v0;
      *(short8*)&Klds[kr * 136 + kseg * 16 + 8] = v1;
    }
    {  // stage V tile transposed: Vlds[n][k]
#pragma unroll
      for (int i = 0; i < 4; ++i) {
        int c = tid + i * 256;
        int r = c >> 5, n8 = (c & 31) * 8;
        const u16* src = kv + ((size_t)b * S_LEN + kk0 + r) * 2560 + 512 + h * 256 + n8;
        short8 v = *(const short8*)src;
#pragma unroll
        for (int j = 0; j < 8; ++j) Vlds[(n8 + j) * 40 + r] = (u16)v[j];
      }
    }
    __syncthreads();

    // S = Q K^T for 32 k-cols (two 16x16 tiles)
    floatx4 s0 = {0.f, 0.f, 0.f, 0.f}, s1 = {0.f, 0.f, 0.f, 0.f};
#pragma unroll
    for (int c = 0; c < 4; ++c) {
      short8 k0f = *(const short8*)&Klds[lane15 * 136 + c * 32 + quad * 8];
      s0 = mfma16(qfrag[c], k0f, s0);
      short8 k1f = *(const short8*)&Klds[(16 + lane15) * 136 + c * 32 + quad * 8];
      s1 = mfma16(qfrag[c], k1f, s1);
    }

    float alpha[4];
#pragma unroll
    for (int r = 0; r < 4; ++r) {
      float a0 = s0[r] * scale, a1 = s1[r] * scale;
      float mx = fmaxf(a0, a1);
#pragma unroll
      for (int d = 1; d < 16; d <<= 1) mx = fmaxf(mx, __shfl_xor(mx, d));
      float mnew = fmaxf(m_i[r], mx);
      float al = __expf(m_i[r] - mnew);
      float p0 = __expf(a0 - mnew);
      float p1 = __expf(a1 - mnew);
      float rs = p0 + p1;
#pragma unroll
      for (int d = 1; d < 16; d <<= 1) rs += __shfl_xor(rs, d);
      m_i[r] = mnew;
      l_i[r] = l_i[r] * al + rs;
      alpha[r] = al;
      int row = quad * 4 + r;  // D layout -> P row
      Plds[wave][row * 40 + lane15] = f2bf(p0);
      Plds[wave][row * 40 + 16 + lane15] = f2bf(p1);
    }
    // wave-internal LDS RAW: DS ops in-order within a wave; compiler inserts lgkmcnt
    short8 pfrag = *(const short8*)&Plds[wave][lane15 * 40 + quad * 8];

#pragma unroll
    for (int g = 0; g < 16; ++g) {
      floatx4 o = o_acc[g];
      o[0] *= alpha[0]; o[1] *= alpha[1]; o[2] *= alpha[2]; o[3] *= alpha[3];
      short8 vf = *(const short8*)&Vlds[(g * 16 + lane15) * 40 + quad * 8];
      o_acc[g] = mfma16(pfrag, vf, o);
    }
  }

  float inv_l[4];
#pragma unroll
  for (int r = 0; r < 4; ++r) inv_l[r] = 1.0f / l_i[r];
#pragma unroll
  for (int g = 0; g < 16; ++g) {
#pragma unroll
    for (int r = 0; r < 4; ++r) {
      int row = qrow0 + quad * 4 + r;
      int col = h * 256 + g * 16 + lane15;
      attn_out[((size_t)b * S_LEN + row) * 2048 + col] = f2bf(o_acc[g][r] * inv_l[r]);
    }
  }
}

extern "C" void kernel_launch(void* const* d_in, const int* in_sizes, int n_in,
                              void* d_out, int out_size, void* d_ws, size_t ws_size,
                              hipStream_t stream) {
  const float* x = (const float*)d_in[0];
  const int* pos = (const int*)d_in[1];
  const float* wdq = (const float*)d_in[2];
  const float* bdq = (const float*)d_in[3];
  const float* qnw = (const float*)d_in[4];
  const float* wuq = (const float*)d_in[5];
  const float* buq = (const float*)d_in[6];
  const float* wdkv = (const float*)d_in[7];
  const float* bdkv = (const float*)d_in[8];
  const float* kvnw = (const float*)d_in[9];
  const float* wukv = (const float*)d_in[10];
  const float* bukv = (const float*)d_in[11];
  const float* wo = (const float*)d_in[12];
  const float* bo = (const float*)d_in[13];
  float* out = (float*)d_out;

  char* ws = (char*)d_ws;
  size_t off = 0;
  auto alloc = [&](size_t bytes) {
    char* p = ws + off;
    off += (bytes + 255) & ~(size_t)255;
    return p;
  };
  u16* xbf = (u16*)alloc((size_t)R_TOK * 1024 * 2);
  u16* wA = (u16*)alloc((size_t)1024 * 320 * 2);
  float* biasA = (float*)alloc(320 * 4);
  u16* wQ = (u16*)alloc((size_t)128 * 1024 * 2);
  u16* wKV = (u16*)alloc((size_t)128 * 2560 * 2);
  u16* wO = (u16*)alloc((size_t)2048 * 1024 * 2);
  float* t0 = (float*)alloc((size_t)R_TOK * 320 * 4);
  u16* cq = (u16*)alloc((size_t)R_TOK * 128 * 2);
  u16* ckv = (u16*)alloc((size_t)R_TOK * 128 * 2);
  u16* krope = (u16*)alloc((size_t)R_TOK * 64 * 2);
  u16* qout = (u16*)alloc((size_t)R_TOK * 1024 * 2);
  u16* qst = (u16*)alloc((size_t)R_TOK * 1024 * 2);
  u16* kvb = (u16*)alloc((size_t)R_TOK * 2560 * 2);
  u16* attnb = (u16*)alloc((size_t)R_TOK * 2048 * 2);
  (void)ws_size; (void)n_in; (void)in_sizes; (void)out_size;

  // converts / weight prep
  k_f2bf<<<(R_TOK * 1024 / 4 + 255) / 256, 256, 0, stream>>>(x, xbf, R_TOK * 1024 / 4);
  k_prep_wa<<<(1024 * 320 + 255) / 256, 256, 0, stream>>>(wdq, wdkv, bdq, bdkv, wA, biasA);
  k_f2bf<<<(128 * 1024 / 4 + 255) / 256, 256, 0, stream>>>(wuq, wQ, 128 * 1024 / 4);
  k_f2bf<<<(128 * 2560 / 4 + 255) / 256, 256, 0, stream>>>(wukv, wKV, 128 * 2560 / 4);
  k_f2bf<<<(2048 * 1024 / 4 + 255) / 256, 256, 0, stream>>>(wo, wO, 2048 * 1024 / 4);

  // stage A: x @ [w_dq | w_dkv_kr] -> t0 fp32
  k_gemm<0><<<dim3(5, 64), 256, 0, stream>>>(xbf, wA, biasA, t0, R_TOK, 320, 1024);
  k_stagea<<<R_TOK, 128, 0, stream>>>(t0, qnw, kvnw, pos, cq, ckv, krope);
  // stage B: q up-proj, rope+scatter
  k_gemm<1><<<dim3(16, 64), 256, 0, stream>>>(cq, wQ, buq, qout, R_TOK, 1024, 128);
  k_stageb<<<R_TOK, 256, 0, stream>>>(qout, pos, qst);
  // kv up-proj
  k_gemm<1><<<dim3(40, 64), 256, 0, stream>>>(ckv, wKV, bukv, kvb, R_TOK, 2560, 128);
  // attention
  k_attn<<<dim3(32, 16), 256, 0, stream>>>(qst, kvb, krope, attnb);
  // output projection -> fp32 out
  k_gemm<0><<<dim3(16, 64), 256, 0, stream>>>(attnb, wO, bo, out, R_TOK, 1024, 2048);
}

// Round 2
// 471.029 us; speedup vs baseline: 1.7962x; 1.7962x over previous
//
#include <hip/hip_runtime.h>
#include <stdint.h>

typedef unsigned short u16;
typedef short short8 __attribute__((ext_vector_type(8)));
typedef float floatx4 __attribute__((ext_vector_type(4)));

#define S_LEN 2048
#define NB 2
#define NH 8
#define R_TOK (NB * S_LEN)  // 4096

// log2(10000)
#define L2_THETA 13.287712379549449f

__device__ inline u16 f2bf(float f) {
  union { float f; uint32_t u; } x; x.f = f;
  uint32_t r = (x.u + 0x7fffu + ((x.u >> 16) & 1u)) >> 16;
  return (u16)r;
}
__device__ inline float bf2f(u16 h) {
  union { uint32_t u; float f; } x; x.u = ((uint32_t)h) << 16;
  return x.f;
}
__device__ inline floatx4 mfma16(short8 a, short8 b, floatx4 c) {
  return __builtin_amdgcn_mfma_f32_16x16x32_bf16(a, b, c, 0, 0, 0);
}

// ---------------- fp32 -> bf16 convert (vectorized) ----------------
__global__ void k_f2bf(const float* __restrict__ in, u16* __restrict__ out, int n4) {
  int i = blockIdx.x * blockDim.x + threadIdx.x;
  if (i < n4) {
    float4 v = ((const float4*)in)[i];
    ushort4 o;
    o.x = f2bf(v.x); o.y = f2bf(v.y); o.z = f2bf(v.z); o.w = f2bf(v.w);
    ((ushort4*)out)[i] = o;
  }
}

// ---------------- concat [w_dq | w_dkv_kr] -> bf16 (1024 x 320), concat bias ----------------
__global__ void k_prep_wa(const float* __restrict__ wdq, const float* __restrict__ wdkv,
                          const float* __restrict__ bdq, const float* __restrict__ bdkv,
                          u16* __restrict__ wa, float* __restrict__ biasA) {
  int i = blockIdx.x * 256 + threadIdx.x;
  if (i < 1024 * 320) {
    int k = i / 320, n = i - k * 320;
    float v = (n < 128) ? wdq[k * 128 + n] : wdkv[k * 192 + (n - 128)];
    wa[i] = f2bf(v);
  }
  if (i < 320) biasA[i] = (i < 128) ? bdq[i] : bdkv[i - 128];
}

// ---------------- generic bf16 MFMA GEMM: C(MxN) = A(MxK) @ B(KxN) + bias ----------------
template <int OUT_BF>
__global__ __launch_bounds__(256) void k_gemm(const u16* __restrict__ A,
                                              const u16* __restrict__ Bm,
                                              const float* __restrict__ bias,
                                              void* __restrict__ Cout,
                                              int M, int N, int K) {
  __shared__ u16 Alds[64 * 40];
  __shared__ u16 Blds[64 * 40];
  const int tid = threadIdx.x;
  const int wave = tid >> 6, lane = tid & 63;
  const int lane15 = lane & 15, quad = lane >> 4;
  const int m0 = blockIdx.y * 64, n0 = blockIdx.x * 64;

  floatx4 acc[4];
#pragma unroll
  for (int i = 0; i < 4; ++i) acc[i] = (floatx4){0.f, 0.f, 0.f, 0.f};

  const int ar = tid >> 2, aseg = (tid & 3) * 8;
  const int bk = tid >> 3, bn8 = (tid & 7) * 8;

  for (int k0 = 0; k0 < K; k0 += 32) {
    __syncthreads();
    {
      const u16* src = A + (size_t)(m0 + ar) * K + k0 + aseg;
      *(short8*)&Alds[ar * 40 + aseg] = *(const short8*)src;
    }
    {
      const u16* src = Bm + (size_t)(k0 + bk) * N + n0 + bn8;
      short8 v = *(const short8*)src;
#pragma unroll
      for (int j = 0; j < 8; ++j) Blds[(bn8 + j) * 40 + bk] = (u16)v[j];
    }
    __syncthreads();
    short8 a = *(const short8*)&Alds[(wave * 16 + lane15) * 40 + quad * 8];
#pragma unroll
    for (int nb = 0; nb < 4; ++nb) {
      short8 b = *(const short8*)&Blds[(nb * 16 + lane15) * 40 + quad * 8];
      acc[nb] = mfma16(a, b, acc[nb]);
    }
  }
#pragma unroll
  for (int nb = 0; nb < 4; ++nb) {
#pragma unroll
    for (int r = 0; r < 4; ++r) {
      int row = m0 + wave * 16 + quad * 4 + r;
      int col = n0 + nb * 16 + lane15;
      float v = acc[nb][r] + bias[col];
      if (OUT_BF)
        ((u16*)Cout)[(size_t)row * N + col] = f2bf(v);
      else
        ((float*)Cout)[(size_t)row * N + col] = v;
    }
  }
}

// ---------------- stage-A epilogue: rmsnorm(cq), rmsnorm(ckv), rope(k_rope) ----------------
__global__ void k_stagea(const float* __restrict__ t0, const float* __restrict__ qnw,
                         const float* __restrict__ kvnw, const int* __restrict__ pos_ids,
                         u16* __restrict__ cq, u16* __restrict__ ckv,
                         u16* __restrict__ krope) {
  int r = blockIdx.x, tid = threadIdx.x;  // 128 threads
  const float* row = t0 + (size_t)r * 320;
  float a = row[tid];
  float b = row[128 + tid];
  float sa = a * a, sb = b * b;
#pragma unroll
  for (int d = 1; d < 64; d <<= 1) {
    sa += __shfl_xor(sa, d);
    sb += __shfl_xor(sb, d);
  }
  __shared__ float red[4];
  if ((tid & 63) == 0) { red[(tid >> 6) * 2] = sa; red[(tid >> 6) * 2 + 1] = sb; }
  __syncthreads();
  sa = red[0] + red[2];
  sb = red[1] + red[3];
  float ra = rsqrtf(sa * (1.0f / 128.0f) + 1e-8f);
  float rb = rsqrtf(sb * (1.0f / 128.0f) + 1e-8f);
  cq[(size_t)r * 128 + tid] = f2bf(qnw[tid] * a * ra);
  ckv[(size_t)r * 128 + tid] = f2bf(kvnw[tid] * b * rb);
  if (tid < 32) {
    float xe = row[256 + 2 * tid], xo = row[256 + 2 * tid + 1];
    float p = (float)pos_ids[r];
    float freq = exp2f(-(2.0f * tid / 64.0f) * L2_THETA);
    float ang = p * freq;
    float c = cosf(ang), s = sinf(ang);
    krope[(size_t)r * 64 + 2 * tid] = f2bf(xe * c - xo * s);
    krope[(size_t)r * 64 + 2 * tid + 1] = f2bf(xe * s + xo * c);
  }
}

// ---------------- stage-B epilogue: rope(q_rope) + scatter to (B,H,S,128) ----------------
__global__ void k_stageb(const u16* __restrict__ q, const int* __restrict__ pos_ids,
                         u16* __restrict__ qstates) {
  int r = blockIdx.x, tid = threadIdx.x;  // 256 threads
  int b = r >> 11, s = r & (S_LEN - 1);
  float p = (float)pos_ids[r];
#pragma unroll
  for (int i = 0; i < 4; ++i) {
    int idx = tid + i * 256;  // h*128 + d
    int h = idx >> 7, d = idx & 127;
    float val;
    if (d < 96) {
      val = bf2f(q[(size_t)r * 1024 + h * 96 + d]);
    } else {
      int j = d - 96, pr = j >> 1;
      float xe = bf2f(q[(size_t)r * 1024 + 768 + h * 32 + 2 * pr]);
      float xo = bf2f(q[(size_t)r * 1024 + 768 + h * 32 + 2 * pr + 1]);
      float freq = exp2f(-(2.0f * pr / 32.0f) * L2_THETA);
      float ang = p * freq;
      float c = cosf(ang), sn = sinf(ang);
      val = (j & 1) ? (xe * sn + xo * c) : (xe * c - xo * sn);
    }
    qstates[((size_t)(b * NH + h) * S_LEN + s) * 128 + d] = f2bf(val);
  }
}

// ---------------- flash attention ----------------
// Block = (b,h) x 64 q-rows, 4 waves (16 q-rows each). K-chunk = 64.
// LDS layouts XOR-swizzled at 16B-unit granularity -> conflict-free stage+read.
// Klds: 64 rows x 128 hw (nope|rope), unit u' = (u&8)|((u^row)&7)
// Vlds: transposed [n=256][k=64], unit u' = (u ^ (n>>3) ^ n)&7
__device__ inline int kaddr(int row, int u) {
  return row * 128 + (((u & 8) | ((u ^ row) & 7)) << 3);
}
__device__ inline int vaddr(int n, int u) {
  return n * 64 + (((u ^ (n >> 3) ^ n) & 7) << 3);
}

__global__ __launch_bounds__(256) void k_attn(const u16* __restrict__ qstates,
                                              const u16* __restrict__ kv,
                                              const u16* __restrict__ krope,
                                              u16* __restrict__ attn_out) {
  const int qblk = blockIdx.x;  // 0..31
  const int pair = blockIdx.y;  // 0..15
  const int b = pair >> 3, h = pair & 7;
  const int tid = threadIdx.x;
  const int wave = tid >> 6, lane = tid & 63;
  const int lane15 = lane & 15, quad = lane >> 4;

  __shared__ __align__(16) u16 Klds[64 * 128];      // 16 KB
  __shared__ __align__(16) u16 Vlds[256 * 64];      // 32 KB
  __shared__ __align__(16) u16 Plds[4][16 * 72];    // 9 KB, stride 72

  const int qrow0 = qblk * 64 + wave * 16;
  short8 qfrag[4];
  {
    const u16* qb = qstates + ((size_t)(b * NH + h) * S_LEN + qrow0 + lane15) * 128 + quad * 8;
#pragma unroll
    for (int c = 0; c < 4; ++c) qfrag[c] = *(const short8*)(qb + c * 32);
  }

  floatx4 o_acc[16];
#pragma unroll
  for (int g = 0; g < 16; ++g) o_acc[g] = (floatx4){0.f, 0.f, 0.f, 0.f};
  float m_i[4] = {-1e30f, -1e30f, -1e30f, -1e30f};
  float l_i[4] = {0.f, 0.f, 0.f, 0.f};
  const float scale = 0.08838834764831845f;  // 1/sqrt(128)

  // staging assignments
  const int kr = tid >> 2, q4 = tid & 3;         // K: 64 rows x 4 quarters (32 hw each)
  const int vn8 = (tid & 31) * 8, vkb = tid >> 5; // V: 32 n-groups x 8 k-groups

  for (int kk0 = 0; kk0 < S_LEN; kk0 += 64) {
    __syncthreads();
    {  // stage K tile: 64 rows x 128 hw (k_nope | k_rope), swizzled b128 writes
      size_t rowg = (size_t)b * S_LEN + kk0 + kr;
      const u16* srcK = (q4 < 2) ? (kv + rowg * 2560 + h * 64 + q4 * 32)
                                 : (krope + rowg * 64 + (q4 - 2) * 32);
#pragma unroll
      for (int s = 0; s < 4; ++s) {
        short8 v = *(const short8*)(srcK + s * 8);
        *(short8*)&Klds[kaddr(kr, q4 * 4 + s)] = v;
      }
    }
    {  // stage V tile transposed via in-register 8x8 u16 transpose (v_perm)
      const u16* srcV = kv + ((size_t)b * S_LEN + kk0 + vkb * 8) * 2560 + 512 + h * 256 + vn8;
      uint32_t u[8][4];
#pragma unroll
      for (int i = 0; i < 8; ++i) {
        uint4 w = *(const uint4*)(srcV + (size_t)i * 2560);
        u[i][0] = w.x; u[i][1] = w.y; u[i][2] = w.z; u[i][3] = w.w;
      }
#pragma unroll
      for (int j = 0; j < 8; ++j) {
        uint32_t sel = (j & 1) ? 0x07060302u : 0x05040100u;
        int jh = j >> 1;
        uint4 o;
        o.x = __builtin_amdgcn_perm(u[1][jh], u[0][jh], sel);
        o.y = __builtin_amdgcn_perm(u[3][jh], u[2][jh], sel);
        o.z = __builtin_amdgcn_perm(u[5][jh], u[4][jh], sel);
        o.w = __builtin_amdgcn_perm(u[7][jh], u[6][jh], sel);
        *(uint4*)&Vlds[vaddr(vn8 + j, vkb)] = o;
      }
    }
    __syncthreads();

    // S = Q K^T : 4 tiles of 16 k-cols
    floatx4 st[4];
#pragma unroll
    for (int t = 0; t < 4; ++t) st[t] = (floatx4){0.f, 0.f, 0.f, 0.f};
#pragma unroll
    for (int c = 0; c < 4; ++c) {
      short8 a = qfrag[c];
#pragma unroll
      for (int t = 0; t < 4; ++t) {
        short8 kf = *(const short8*)&Klds[kaddr(t * 16 + lane15, c * 4 + quad)];
        st[t] = mfma16(a, kf, st[t]);
      }
    }

    float alpha[4];
#pragma unroll
    for (int r = 0; r < 4; ++r) {
      float a0 = st[0][r] * scale, a1 = st[1][r] * scale;
      float a2 = st[2][r] * scale, a3 = st[3][r] * scale;
      float mx = fmaxf(fmaxf(a0, a1), fmaxf(a2, a3));
#pragma unroll
      for (int d = 1; d < 16; d <<= 1) mx = fmaxf(mx, __shfl_xor(mx, d));
      float mnew = fmaxf(m_i[r], mx);
      float al = __expf(m_i[r] - mnew);
      float p0 = __expf(a0 - mnew), p1 = __expf(a1 - mnew);
      float p2 = __expf(a2 - mnew), p3 = __expf(a3 - mnew);
      float rs = (p0 + p1) + (p2 + p3);
#pragma unroll
      for (int d = 1; d < 16; d <<= 1) rs += __shfl_xor(rs, d);
      m_i[r] = mnew;
      l_i[r] = l_i[r] * al + rs;
      alpha[r] = al;
      int prow = quad * 4 + r;  // D layout -> P row
      Plds[wave][prow * 72 + lane15] = f2bf(p0);
      Plds[wave][prow * 72 + 16 + lane15] = f2bf(p1);
      Plds[wave][prow * 72 + 32 + lane15] = f2bf(p2);
      Plds[wave][prow * 72 + 48 + lane15] = f2bf(p3);
    }
    // wave-internal RAW through LDS: in-order DS + compiler lgkmcnt
    short8 pf0 = *(const short8*)&Plds[wave][lane15 * 72 + quad * 8];
    short8 pf1 = *(const short8*)&Plds[wave][lane15 * 72 + 32 + quad * 8];

#pragma unroll
    for (int g = 0; g < 16; ++g) {
      floatx4 o = o_acc[g];
      o[0] *= alpha[0]; o[1] *= alpha[1]; o[2] *= alpha[2]; o[3] *= alpha[3];
      int n = g * 16 + lane15;
      short8 v0 = *(const short8*)&Vlds[vaddr(n, quad)];
      short8 v1 = *(const short8*)&Vlds[vaddr(n, 4 + quad)];
      o = mfma16(pf0, v0, o);
      o = mfma16(pf1, v1, o);
      o_acc[g] = o;
    }
  }

  float inv_l[4];
#pragma unroll
  for (int r = 0; r < 4; ++r) inv_l[r] = 1.0f / l_i[r];
#pragma unroll
  for (int g = 0; g < 16; ++g) {
#pragma unroll
    for (int r = 0; r < 4; ++r) {
      int row = qrow0 + quad * 4 + r;
      int col = h * 256 + g * 16 + lane15;
      attn_out[((size_t)b * S_LEN + row) * 2048 + col] = f2bf(o_acc[g][r] * inv_l[r]);
    }
  }
}

extern "C" void kernel_launch(void* const* d_in, const int* in_sizes, int n_in,
                              void* d_out, int out_size, void* d_ws, size_t ws_size,
                              hipStream_t stream) {
  const float* x = (const float*)d_in[0];
  const int* pos = (const int*)d_in[1];
  const float* wdq = (const float*)d_in[2];
  const float* bdq = (const float*)d_in[3];
  const float* qnw = (const float*)d_in[4];
  const float* wuq = (const float*)d_in[5];
  const float* buq = (const float*)d_in[6];
  const float* wdkv = (const float*)d_in[7];
  const float* bdkv = (const float*)d_in[8];
  const float* kvnw = (const float*)d_in[9];
  const float* wukv = (const float*)d_in[10];
  const float* bukv = (const float*)d_in[11];
  const float* wo = (const float*)d_in[12];
  const float* bo = (const float*)d_in[13];
  float* out = (float*)d_out;

  char* ws = (char*)d_ws;
  size_t off = 0;
  auto alloc = [&](size_t bytes) {
    char* p = ws + off;
    off += (bytes + 255) & ~(size_t)255;
    return p;
  };
  u16* xbf = (u16*)alloc((size_t)R_TOK * 1024 * 2);
  u16* wA = (u16*)alloc((size_t)1024 * 320 * 2);
  float* biasA = (float*)alloc(320 * 4);
  u16* wQ = (u16*)alloc((size_t)128 * 1024 * 2);
  u16* wKV = (u16*)alloc((size_t)128 * 2560 * 2);
  u16* wO = (u16*)alloc((size_t)2048 * 1024 * 2);
  float* t0 = (float*)alloc((size_t)R_TOK * 320 * 4);
  u16* cq = (u16*)alloc((size_t)R_TOK * 128 * 2);
  u16* ckv = (u16*)alloc((size_t)R_TOK * 128 * 2);
  u16* krope = (u16*)alloc((size_t)R_TOK * 64 * 2);
  u16* qout = (u16*)alloc((size_t)R_TOK * 1024 * 2);
  u16* qst = (u16*)alloc((size_t)R_TOK * 1024 * 2);
  u16* kvb = (u16*)alloc((size_t)R_TOK * 2560 * 2);
  u16* attnb = (u16*)alloc((size_t)R_TOK * 2048 * 2);
  (void)ws_size; (void)n_in; (void)in_sizes; (void)out_size;

  // converts / weight prep
  k_f2bf<<<(R_TOK * 1024 / 4 + 255) / 256, 256, 0, stream>>>(x, xbf, R_TOK * 1024 / 4);
  k_prep_wa<<<(1024 * 320 + 255) / 256, 256, 0, stream>>>(wdq, wdkv, bdq, bdkv, wA, biasA);
  k_f2bf<<<(128 * 1024 / 4 + 255) / 256, 256, 0, stream>>>(wuq, wQ, 128 * 1024 / 4);
  k_f2bf<<<(128 * 2560 / 4 + 255) / 256, 256, 0, stream>>>(wukv, wKV, 128 * 2560 / 4);
  k_f2bf<<<(2048 * 1024 / 4 + 255) / 256, 256, 0, stream>>>(wo, wO, 2048 * 1024 / 4);

  // stage A: x @ [w_dq | w_dkv_kr] -> t0 fp32
  k_gemm<0><<<dim3(5, 64), 256, 0, stream>>>(xbf, wA, biasA, t0, R_TOK, 320, 1024);
  k_stagea<<<R_TOK, 128, 0, stream>>>(t0, qnw, kvnw, pos, cq, ckv, krope);
  // stage B: q up-proj, rope+scatter
  k_gemm<1><<<dim3(16, 64), 256, 0, stream>>>(cq, wQ, buq, qout, R_TOK, 1024, 128);
  k_stageb<<<R_TOK, 256, 0, stream>>>(qout, pos, qst);
  // kv up-proj
  k_gemm<1><<<dim3(40, 64), 256, 0, stream>>>(ckv, wKV, bukv, kvb, R_TOK, 2560, 128);
  // attention
  k_attn<<<dim3(32, 16), 256, 0, stream>>>(qst, kvb, krope, attnb);
  // output projection -> fp32 out
  k_gemm<0><<<dim3(16, 64), 256, 0, stream>>>(attnb, wO, bo, out, R_TOK, 1024, 2048);
}